// Round 6
// baseline (124.907 us; speedup 1.0000x reference)
//
#include <hip/hip_runtime.h>

// Fused UpFIRDn2d via banded MFMA chain: crop(1) -> +bias -> repeat-up x2 ->
// sep 12-tap FIR -> leaky_relu(0.2)*sqrt(2) -> sep 12-tap FIR -> down x2.
// x: (8,64,130,130) f32; out: (8,64,128,128) f32.
//
// Round 12: column-chain restructure (convoy breaker). Rounds 8-11 proved
// duration (~50us) invariant under occupancy, barriers, ILP and VALU count:
// no pipe >55% busy, wave lifetime ~8.7us vs ~0.6us issued work -> the
// barrier-locked phases convoy all resident waves onto the same pipe then
// stall together. Fix: qq-column ownership. Wave w owns qq columns
// [16w,16w+16): S1 (5 tiles) -> S2 (9 tiles) -> S3 (4 tiles) is then
// WAVE-PRIVATE (S2/S3 read only their own column of B1/U) -> no barriers,
// 5 independent 18-tile chains that desync. Only 2 barriers: after P0 and
// before S4 (T consumed cross-column). Ut is eliminated: S3 B-frags built
// in-register from S2 C-frags via ds_bpermute (8 bperm + 4 cndmask per
// frag; algebra: word w, dest q4': pp0 = s+8q4'+2w lives in lane
// (l15, (2q4'+(w>>1))&3) word delta=w&1 of tile s/16 + (q4'>>1)).
// 320 thr = 5 waves; LDS 32000B (Xl 48x80 | 5x B1-slice [16][88] | T 64x80)
// -> 5 blocks/CU = 25 waves. Grid (4,2,512) = 4096 blocks.
//   S1: B1[r][qq]  = sum_c  X[r][c]   * Gt[c][qq]    Kwin32, 5 tiles/wave
//   S2: U [pp][qq] = sum_r  G2[pp][r] * B1[r][qq]    Kwin32, 9 tiles/wave, leaky
//   S3: T [a][qq]  = sum_pp D[a][pp]  * U[pp][qq]    Kwin64, 4 tiles/wave
//   S4: Out[a][j]  = sum_qq T[a][qq]  * D2t[qq][j]   Kwin64, 8 tiles/block
// Edge clipping folded into 2 variants of D (by) and 3 of D2t (bx).

#define GAIN_C 1.4142135623730951f
#define NEG_C ((0.2f - 1.0f) * GAIN_C)

typedef short v8s __attribute__((ext_vector_type(8)));
typedef float v4f __attribute__((ext_vector_type(4)));

__device__ __forceinline__ int f2bf(float f) {   // fp32 -> bf16 bits (RNE)
    unsigned u = __float_as_uint(f);
    return (int)((u + 0x7FFFu + ((u >> 16) & 1u)) >> 16) & 0xFFFF;
}
__device__ __forceinline__ int pack_bf2(float a, float b) {
#if __has_builtin(__builtin_amdgcn_cvt_pk_bf16_f32)
    typedef __bf16 bf2 __attribute__((ext_vector_type(2)));
    bf2 r = __builtin_amdgcn_cvt_pk_bf16_f32(a, b);
    int o; __builtin_memcpy(&o, &r, 4); return o;
#else
    return f2bf(a) | (f2bf(b) << 16);
#endif
}

// band(x, q): up-conv weight linking local input index x to local up index q.
// qlim/xlim: valid extents of the local windows (cols: 74/43, rows: 138/75).
__device__ float band(int x, int q, int qlim, int xlim, const float* fu) {
    if (q >= qlim || x >= xlim || x < 0) return 0.f;
    int p = q >> 1, d = x - p;
    if (q & 1) {
        if (d < 0 || d > 6) return 0.f;
        if (d == 0) return fu[0];
        if (d == 6) return fu[11];
        return fu[2 * d - 1] + fu[2 * d];
    } else {
        if (d < 0 || d > 5) return 0.f;
        return fu[2 * d] + fu[2 * d + 1];
    }
}
// dband(o, q, v): down-conv weight, out index o, up index q; variant v:
// 0 = first tile (zero q<5), 2 = last tile (zero q>=qlim-5). qlim = up extent.
__device__ float dband(int o, int q, int v, int qlim, const float* fd) {
    if (q >= qlim || q < 0) return 0.f;
    if (v == 0 && q < 5) return 0.f;
    if (v == 2 && q >= qlim - 5) return 0.f;
    int k = q - 2 * o;
    if (k < 0 || k > 11) return 0.f;
    return fd[k];
}

// ws layout (bf16): UNCHANGED from round 10/11.
//   GtB 5nt x512            @0       (cols up: qlim 74, xlim 43, k0=min(8nt,16))
//   G2A 9mt x512            @2560    (rows up: qlim 138, xlim 75, k0=min(8mt,48))
//   DA  2v x (4mt x 2kt)x512 @7168   (rows dn: qlim 138, k0=min(32mt,80))
//   D2B 3v x (2nt x 2kt)x512 @15360  (cols dn: qlim 74,  k0=nt?16:0)
// Total 21504 shorts.
__global__ __launch_bounds__(256) void build_consts(
    const float* __restrict__ fu, const float* __restrict__ fd,
    short* __restrict__ ws)
{
    int idx = blockIdx.x * 256 + threadIdx.x;   // grid covers 21504 exactly
    int l = (idx >> 3) & 63, j = idx & 7;
    int l15 = l & 15, kq = (l >> 4) * 8 + j;
    float val;
    if (idx < 2560) {                         // GtB: B-op, frag = nt
        int nt = idx >> 9;
        int k0 = 8 * nt < 16 ? 8 * nt : 16;
        val = band(k0 + kq, 16 * nt + l15, 74, 43, fu);
    } else if (idx < 7168) {                  // G2A: A-op, frag = mt (0..8)
        int mt = (idx - 2560) >> 9;
        int k0 = 8 * mt < 48 ? 8 * mt : 48;
        val = band(k0 + kq, 16 * mt + l15, 138, 75, fu);
    } else if (idx < 15360) {                 // DA: A-op, frag = (v, mt*2+kt)
        int rel = idx - 7168;
        int v = (rel >> 12) ? 2 : 0;          // by=0 -> v0, by=1 -> v2
        int fi = (rel & 4095) >> 9;
        int mt = fi >> 1, kt = fi & 1;
        int k0 = 32 * mt < 80 ? 32 * mt : 80;
        val = dband(16 * mt + l15, k0 + 32 * kt + kq, v, 138, fd);
    } else {                                  // D2B: B-op, frag = (v, nt*2+kt)
        int rel = idx - 15360;
        int v = rel >> 11, fi = (rel & 2047) >> 9;
        int nt = fi >> 1, kt = fi & 1;
        int k0 = nt ? 16 : 0;
        val = dband(16 * nt + l15, k0 + 32 * kt + kq, v, 74, fd);
    }
    ws[idx] = (short)f2bf(val);
}

#define XPITCH 48   // Xl [80 r][48 c]; 24 words/row: period-4, 2-way (free)
#define BPITCH 88   // B1 slice [16 qq][88 r]; 44 words/row: period-8
#define TPITCH 80   // T [64 a][80 qq]

// LDS (shorts): Xl @0 (3840) | B1 slices @3840 (5 x 1408) | T @10880 (5120).
// Total 16000 shorts = 32000 B -> 5 blocks/CU (160 KB), 25 waves/CU.
__global__ __launch_bounds__(320, 6) void upfirdn_mfma(
    const float* __restrict__ xin_all,
    const float* __restrict__ bias,
    const short* __restrict__ cws,
    float* __restrict__ out)
{
    __shared__ __align__(16) short SH[16000];
    short* Xl = SH;                       // [80][48]
    short* T  = SH + 10880;               // [64][80]

    const int tid  = threadIdx.x;
    const int lane = tid & 63, w = tid >> 6;          // 5 waves, w = nt
    const int l15  = lane & 15, q4 = lane >> 4;
    const int bx = blockIdx.x, by = blockIdx.y, bc = blockIdx.z;
    const int i0 = by * 64, j0 = bx * 32;

    short* Bsl = SH + 3840 + w * 1408;    // this wave's private B1 [16][88]

    const short* GtB = cws;
    const short* G2A = cws + 2560;
    const short* DA  = cws + 7168  + (by ? 4096 : 0);
    const short* D2B = cws + 15360 + ((bx == 0) ? 0 : (bx == 3) ? 2 : 1) * 2048;

    // ---- Phase 0: load X tile (crop +1, +bias), pads zero. 80 rows x 24 ints,
    // ---- 6 threads/row x 8 cols; 480 slots over 320 threads. ----
    {
        const float* xp = xin_all + (size_t)bc * (130 * 130);
        const float bv = bias[bc & 63];
        const bool colInt = (bx == 1) | (bx == 2);
        for (int s = tid; s < 480; s += 320) {
            const int r  = s / 6, c6 = s - 6 * r;
            const int gr = i0 - 5 + r;
            int* dst = (int*)Xl + r * 24 + 4 * c6;
            if (r < 75 && (unsigned)gr < 128u) {
                const float* rowp = xp + (gr + 1) * 130 + 1 + (j0 - 5);
                float f[8];
#pragma unroll
                for (int j = 0; j < 8; ++j) {
                    const int c = 8 * c6 + j;          // local col 0..47
                    bool v = c < 43;
                    if (!colInt) v = v && ((unsigned)(j0 - 5 + c) < 128u);
                    f[j] = v ? rowp[c] + bv : 0.f;
                }
                *(int2*)dst = make_int2(pack_bf2(f[0], f[1]), pack_bf2(f[2], f[3]));
                *(int2*)(dst + 2) =
                    make_int2(pack_bf2(f[4], f[5]), pack_bf2(f[6], f[7]));
            } else {
                *(int2*)dst = make_int2(0, 0);
                *(int2*)(dst + 2) = make_int2(0, 0);
            }
        }
    }
    __syncthreads();

    // ======== Barrier-free per-wave chain: S1 -> S2 -> S3 (column w) ========

    // ---- S1: B1[r][qq col w] = X * Gt, 5 tiles (mt' 0..4) into private slice.
    {
        const int k0c = 8 * w < 16 ? 8 * w : 16;
        v8s bf = *(const v8s*)&GtB[w * 512 + lane * 8];
#pragma unroll
        for (int mt = 0; mt < 5; ++mt) {
            v8s a = *(const v8s*)&Xl[(16 * mt + l15) * XPITCH + k0c + q4 * 8];
            v4f acc = {0.f, 0.f, 0.f, 0.f};
            acc = __builtin_amdgcn_mfma_f32_16x16x32_bf16(a, bf, acc, 0, 0, 0);
            // C: col = qq-local = l15, rows r = 16mt + q4*4 + i
            *(int2*)&Bsl[l15 * BPITCH + 16 * mt + 4 * q4] =
                make_int2(pack_bf2(acc[0], acc[1]), pack_bf2(acc[2], acc[3]));
        }
    }

    // ---- S2: U[pp][qq col w] = leaky(G2 * B1), 9 tiles, kept packed in regs.
    int uw[9][2];
    {
#pragma unroll
        for (int mt = 0; mt < 9; ++mt) {
            const int k0 = 8 * mt < 48 ? 8 * mt : 48;
            v8s af = *(const v8s*)&G2A[mt * 512 + lane * 8];
            v8s b  = *(const v8s*)&Bsl[l15 * BPITCH + k0 + q4 * 8];
            v4f acc = {0.f, 0.f, 0.f, 0.f};
            acc = __builtin_amdgcn_mfma_f32_16x16x32_bf16(af, b, acc, 0, 0, 0);
#pragma unroll
            for (int j = 0; j < 4; ++j)
                acc[j] = GAIN_C * acc[j] + NEG_C * fminf(acc[j], 0.f);
            // lane: col qq = l15, rows pp = 16mt + 4q4 + {0,1,2,3}
            uw[mt][0] = pack_bf2(acc[0], acc[1]);
            uw[mt][1] = pack_bf2(acc[2], acc[3]);
        }
    }

    // ---- S3: T[a][qq col w] = D * U. B-frags built in-register via bpermute.
    // Window [s,s+32), s16=s/16: word w', dest q4: value U[pp0..pp0+1],
    // pp0 = s+8q4+2w' found in lane (l15, (2q4+(w'>>1))&3), word (w'&1),
    // tile s16 + (q4>>1).
    {
        const int idx0 = (l15 + 16 * ((2 * q4) & 3)) * 4;
        const int idx1 = (l15 + 16 * ((2 * q4 + 1) & 3)) * 4;
        const bool hi = (lane >= 32);

#define BUILDF(S16, DST)                                                     \
    {                                                                        \
        int a0 = __builtin_amdgcn_ds_bpermute(idx0, uw[S16][0]);             \
        int b0 = __builtin_amdgcn_ds_bpermute(idx0, uw[(S16) + 1][0]);       \
        int a1 = __builtin_amdgcn_ds_bpermute(idx0, uw[S16][1]);             \
        int b1 = __builtin_amdgcn_ds_bpermute(idx0, uw[(S16) + 1][1]);       \
        int a2 = __builtin_amdgcn_ds_bpermute(idx1, uw[S16][0]);             \
        int b2 = __builtin_amdgcn_ds_bpermute(idx1, uw[(S16) + 1][0]);       \
        int a3 = __builtin_amdgcn_ds_bpermute(idx1, uw[S16][1]);             \
        int b3 = __builtin_amdgcn_ds_bpermute(idx1, uw[(S16) + 1][1]);       \
        union { int i[4]; v8s v; } u_;                                       \
        u_.i[0] = hi ? b0 : a0; u_.i[1] = hi ? b1 : a1;                      \
        u_.i[2] = hi ? b2 : a2; u_.i[3] = hi ? b3 : a3;                      \
        DST = u_.v;                                                          \
    }

        v8s F0, F2, F4, F5, F6, F7;
        BUILDF(0, F0); BUILDF(2, F2); BUILDF(4, F4);
        BUILDF(5, F5); BUILDF(6, F6); BUILDF(7, F7);
#undef BUILDF

#define S3TILE(AMT, FA, FB)                                                  \
    {                                                                        \
        v8s a0 = *(const v8s*)&DA[((AMT) * 2 + 0) * 512 + lane * 8];         \
        v8s a1 = *(const v8s*)&DA[((AMT) * 2 + 1) * 512 + lane * 8];         \
        v4f acc = {0.f, 0.f, 0.f, 0.f};                                      \
        acc = __builtin_amdgcn_mfma_f32_16x16x32_bf16(a0, FA, acc, 0, 0, 0); \
        acc = __builtin_amdgcn_mfma_f32_16x16x32_bf16(a1, FB, acc, 0, 0, 0); \
        int p01 = pack_bf2(acc[0], acc[1]);                                  \
        int p23 = pack_bf2(acc[2], acc[3]);                                  \
        short* tb = &T[(16 * (AMT) + 4 * q4) * TPITCH + 16 * w + l15];       \
        tb[0 * TPITCH] = (short)p01; tb[1 * TPITCH] = (short)(p01 >> 16);    \
        tb[2 * TPITCH] = (short)p23; tb[3 * TPITCH] = (short)(p23 >> 16);    \
    }
        // k0p = min(32*amt, 80): windows (0,32),(32,64),(64,96),(80,112)
        S3TILE(0, F0, F2)
        S3TILE(1, F2, F4)
        S3TILE(2, F4, F6)
        S3TILE(3, F5, F7)
#undef S3TILE
    }
    __syncthreads();

    // ---- S4: Out = T * D2t. 8 tiles: wave w does tile w (+ w+5 if w<3). ----
#pragma unroll
    for (int rep = 0; rep < 2; ++rep) {
        const int q = w + rep * 5;
        if (rep == 1 && w >= 3) break;
        const int mt = q >> 1, nt = q & 1;
        const int k0 = nt ? 16 : 0;
        v8s a0 = *(const v8s*)&T[(16 * mt + l15) * TPITCH + k0 + q4 * 8];
        v8s a1 = *(const v8s*)&T[(16 * mt + l15) * TPITCH + k0 + 32 + q4 * 8];
        v8s b0 = *(const v8s*)&D2B[(nt * 2 + 0) * 512 + lane * 8];
        v8s b1 = *(const v8s*)&D2B[(nt * 2 + 1) * 512 + lane * 8];
        v4f acc = {0.f, 0.f, 0.f, 0.f};
        acc = __builtin_amdgcn_mfma_f32_16x16x32_bf16(a0, b0, acc, 0, 0, 0);
        acc = __builtin_amdgcn_mfma_f32_16x16x32_bf16(a1, b1, acc, 0, 0, 0);
        float* op = out + (size_t)bc * 16384
                  + (size_t)(i0 + 16 * mt + 4 * q4) * 128 + (j0 + 16 * nt + l15);
#pragma unroll
        for (int i = 0; i < 4; ++i) op[i * 128] = acc[i];
    }
}

extern "C" void kernel_launch(void* const* d_in, const int* in_sizes, int n_in,
                              void* d_out, int out_size, void* d_ws, size_t ws_size,
                              hipStream_t stream) {
    const float* x  = (const float*)d_in[0];
    const float* bs = (const float*)d_in[1];
    const float* fu = (const float*)d_in[2];
    const float* fd = (const float*)d_in[3];
    float* outp = (float*)d_out;
    short* ws = (short*)d_ws;

    build_consts<<<84, 256, 0, stream>>>(fu, fd, ws);    // 21504 elems
    upfirdn_mfma<<<dim3(4, 2, 512), 320, 0, stream>>>(x, bs, ws, outp);
}

// Round 7
// 121.546 us; speedup vs baseline: 1.0277x; 1.0277x over previous
//
#include <hip/hip_runtime.h>

// Fused UpFIRDn2d via banded MFMA chain: crop(1) -> +bias -> repeat-up x2 ->
// sep 12-tap FIR -> leaky_relu(0.2)*sqrt(2) -> sep 12-tap FIR -> down x2.
// x: (8,64,130,130) f32; out: (8,64,128,128) f32.
//
// Round 13: force the ILP batch. Round-10 (= round-9 code) measured
// VGPR_Count=32, but a real 6-deep chunk needs ~96 VGPR live -> the compiler
// SANK the batched loads back into the MFMA loop; round-9's experiment never
// ran on hardware. Round-12 (more serialization -> +12us) confirms the
// latency-chain sensitivity. Fix: one __builtin_amdgcn_sched_barrier(0) at
// the load/compute boundary of each chunk (not m141-style full pinning) so
// all K ds_reads issue back-to-back and overlap their ~120cy latency.
// Verification signal: VGPR must rise to >=90; if it stays ~32 the fence was
// defeated and the round is uninterpretable.
// Round-12 lesson (reverted): barrier-free per-wave chains serialize LDS
// round-trips and ds_bpermute ADDS DS-pipe ops (8/frag) -> +12us.
// Round 9/10 base: 64x32 tile, 8 waves (512 thr), grid (4,2,512), compile-
// time chunk sizes per wave, LDS 38.4 KB -> 4 blocks/CU.
//   S1: B1[r][qq]  = sum_c  X[r][c]   * Gt[c][qq]    M80  N80  Kwin32 (25 tiles)
//   S2: U [pp][qq] = sum_r  G2[pp][r] * B1[r][qq]    M144 N80  Kwin32 (45), leaky
//   S3: T [a][qq]  = sum_pp D[a][pp]  * U[pp][qq]    M64  N80  Kwin64 (20)
//   S4: Out[a][j]  = sum_qq T[a][qq]  * D2t[qq][j]   M64  N32  Kwin64 (8)
// Edge clipping folded into 2 variants of D (by) and 3 of D2t (bx).

#define GAIN_C 1.4142135623730951f
#define NEG_C ((0.2f - 1.0f) * GAIN_C)

typedef short v8s __attribute__((ext_vector_type(8)));
typedef float v4f __attribute__((ext_vector_type(4)));

__device__ __forceinline__ int f2bf(float f) {   // fp32 -> bf16 bits (RNE)
    unsigned u = __float_as_uint(f);
    return (int)((u + 0x7FFFu + ((u >> 16) & 1u)) >> 16) & 0xFFFF;
}
__device__ __forceinline__ int pack_bf2(float a, float b) {
#if __has_builtin(__builtin_amdgcn_cvt_pk_bf16_f32)
    typedef __bf16 bf2 __attribute__((ext_vector_type(2)));
    bf2 r = __builtin_amdgcn_cvt_pk_bf16_f32(a, b);
    int o; __builtin_memcpy(&o, &r, 4); return o;
#else
    return f2bf(a) | (f2bf(b) << 16);
#endif
}

// band(x, q): up-conv weight linking local input index x to local up index q.
// qlim/xlim: valid extents of the local windows (cols: 74/43, rows: 138/75).
__device__ float band(int x, int q, int qlim, int xlim, const float* fu) {
    if (q >= qlim || x >= xlim || x < 0) return 0.f;
    int p = q >> 1, d = x - p;
    if (q & 1) {
        if (d < 0 || d > 6) return 0.f;
        if (d == 0) return fu[0];
        if (d == 6) return fu[11];
        return fu[2 * d - 1] + fu[2 * d];
    } else {
        if (d < 0 || d > 5) return 0.f;
        return fu[2 * d] + fu[2 * d + 1];
    }
}
// dband(o, q, v): down-conv weight, out index o, up index q; variant v:
// 0 = first tile (zero q<5), 2 = last tile (zero q>=qlim-5). qlim = up extent.
__device__ float dband(int o, int q, int v, int qlim, const float* fd) {
    if (q >= qlim || q < 0) return 0.f;
    if (v == 0 && q < 5) return 0.f;
    if (v == 2 && q >= qlim - 5) return 0.f;
    int k = q - 2 * o;
    if (k < 0 || k > 11) return 0.f;
    return fd[k];
}

// ws layout (bf16):
//   GtB 5nt x512            @0       (cols up: qlim 74, xlim 43, k0=min(8nt,16))
//   G2A 9mt x512            @2560    (rows up: qlim 138, xlim 75, k0=min(8mt,48))
//   DA  2v x (4mt x 2kt)x512 @7168   (rows dn: qlim 138, k0=min(32mt,80))
//   D2B 3v x (2nt x 2kt)x512 @15360  (cols dn: qlim 74,  k0=nt?16:0)
// Total 21504 shorts.  (Keep in sync with consumer kernel!)
__global__ __launch_bounds__(256) void build_consts(
    const float* __restrict__ fu, const float* __restrict__ fd,
    short* __restrict__ ws)
{
    int idx = blockIdx.x * 256 + threadIdx.x;   // grid covers 21504 exactly
    int l = (idx >> 3) & 63, j = idx & 7;
    int l15 = l & 15, kq = (l >> 4) * 8 + j;
    float val;
    if (idx < 2560) {                         // GtB: B-op, frag = nt
        int nt = idx >> 9;
        int k0 = 8 * nt < 16 ? 8 * nt : 16;
        val = band(k0 + kq, 16 * nt + l15, 74, 43, fu);
    } else if (idx < 7168) {                  // G2A: A-op, frag = mt (0..8)
        int mt = (idx - 2560) >> 9;
        int k0 = 8 * mt < 48 ? 8 * mt : 48;
        val = band(k0 + kq, 16 * mt + l15, 138, 75, fu);
    } else if (idx < 15360) {                 // DA: A-op, frag = (v, mt*2+kt)
        int rel = idx - 7168;
        int v = (rel >> 12) ? 2 : 0;          // by=0 -> v0, by=1 -> v2
        int fi = (rel & 4095) >> 9;
        int mt = fi >> 1, kt = fi & 1;
        int k0 = 32 * mt < 80 ? 32 * mt : 80;
        val = dband(16 * mt + l15, k0 + 32 * kt + kq, v, 138, fd);
    } else {                                  // D2B: B-op, frag = (v, nt*2+kt)
        int rel = idx - 15360;
        int v = rel >> 11, fi = (rel & 2047) >> 9;
        int nt = fi >> 1, kt = fi & 1;
        int k0 = nt ? 16 : 0;
        val = dband(16 * nt + l15, k0 + 32 * kt + kq, v, 74, fd);
    }
    ws[idx] = (short)f2bf(val);
}

#define XPITCH 48    // Xl  [80 r][48 c]    24 words/row (period-4, 2-way: free)
#define BPITCH 88    // B1t [80 qq][88 r]   44 words/row (period-8)
#define UPITCH 152   // Ut  [80 qq][152 pp] 76 words/row (period-8)
#define TPITCH 88    // T   [64 a][88 qq]

// ---- Batched phase chunks: all loads || FENCE || all MFMAs, all writes. ----
// The sched_barrier(0) forbids the scheduler from sinking the loads into the
// MFMA loop (round-10: it did exactly that, VGPR=32 -> serialized chain).
template<int K>
__device__ __forceinline__ void s1_chunk(
    int base, const short* __restrict__ GtB, const short* __restrict__ Xl,
    short* __restrict__ B1t, int lane, int l15, int q4)
{
    v8s a[K], bf[K];
    int dst[K];
#pragma unroll
    for (int i = 0; i < K; ++i) {
        const int t = base + i;
        const int mt = t / 5, nt = t - mt * 5;
        const int k0 = 8 * nt < 16 ? 8 * nt : 16;
        bf[i] = *(const v8s*)&GtB[nt * 512 + lane * 8];
        a[i]  = *(const v8s*)&Xl[(16 * mt + l15) * XPITCH + k0 + q4 * 8];
        dst[i] = (16 * nt + l15) * BPITCH + 16 * mt + q4 * 4;
    }
    __builtin_amdgcn_sched_barrier(0);
#pragma unroll
    for (int i = 0; i < K; ++i) {
        v4f acc = {0.f, 0.f, 0.f, 0.f};
        acc = __builtin_amdgcn_mfma_f32_16x16x32_bf16(a[i], bf[i], acc, 0, 0, 0);
        // C: col = qq = 16nt+l15, rows r = 16mt + q4*4 + i
        *(int2*)&B1t[dst[i]] = make_int2(pack_bf2(acc[0], acc[1]),
                                         pack_bf2(acc[2], acc[3]));
    }
}

template<int K>
__device__ __forceinline__ void s2_chunk(
    int base, const short* __restrict__ G2A, const short* __restrict__ B1t,
    short* __restrict__ Ut, int lane, int l15, int q4)
{
    v8s af[K], b[K];
    int dst[K];
#pragma unroll
    for (int i = 0; i < K; ++i) {
        const int t = base + i;
        const int mt = t / 5, nt = t - mt * 5;
        const int k0 = 8 * mt < 48 ? 8 * mt : 48;
        af[i] = *(const v8s*)&G2A[mt * 512 + lane * 8];
        b[i]  = *(const v8s*)&B1t[(16 * nt + l15) * BPITCH + k0 + q4 * 8];
        dst[i] = (16 * nt + l15) * UPITCH + 16 * mt + q4 * 4;
    }
    __builtin_amdgcn_sched_barrier(0);
#pragma unroll
    for (int i = 0; i < K; ++i) {
        v4f acc = {0.f, 0.f, 0.f, 0.f};
        acc = __builtin_amdgcn_mfma_f32_16x16x32_bf16(af[i], b[i], acc, 0, 0, 0);
#pragma unroll
        for (int j = 0; j < 4; ++j)
            acc[j] = GAIN_C * acc[j] + NEG_C * fminf(acc[j], 0.f);
        // C: col = qq = 16nt+l15, rows pp = 16mt + q4*4 + i
        *(int2*)&Ut[dst[i]] = make_int2(pack_bf2(acc[0], acc[1]),
                                        pack_bf2(acc[2], acc[3]));
    }
}

template<int K>
__device__ __forceinline__ void s3_chunk(
    int base, const short* __restrict__ DA, const short* __restrict__ Ut,
    short* __restrict__ T, int lane, int l15, int q4)
{
    v8s a0[K], a1[K], b0[K], b1[K];
    int mtA[K], ntA[K];
#pragma unroll
    for (int i = 0; i < K; ++i) {
        const int t = base + i;
        const int mt = t / 5, nt = t - mt * 5;
        const int k0 = 32 * mt < 80 ? 32 * mt : 80;
        mtA[i] = mt; ntA[i] = nt;
        a0[i] = *(const v8s*)&DA[(mt * 2 + 0) * 512 + lane * 8];
        a1[i] = *(const v8s*)&DA[(mt * 2 + 1) * 512 + lane * 8];
        b0[i] = *(const v8s*)&Ut[(16 * nt + l15) * UPITCH + k0 + q4 * 8];
        b1[i] = *(const v8s*)&Ut[(16 * nt + l15) * UPITCH + k0 + 32 + q4 * 8];
    }
    __builtin_amdgcn_sched_barrier(0);
#pragma unroll
    for (int i = 0; i < K; ++i) {
        v4f acc = {0.f, 0.f, 0.f, 0.f};
        acc = __builtin_amdgcn_mfma_f32_16x16x32_bf16(a0[i], b0[i], acc, 0, 0, 0);
        acc = __builtin_amdgcn_mfma_f32_16x16x32_bf16(a1[i], b1[i], acc, 0, 0, 0);
        // C: col = qq = 16nt+l15, rows a = 16mt + q4*4 + j  (b16 scatter)
#pragma unroll
        for (int j = 0; j < 4; ++j)
            T[(16 * mtA[i] + q4 * 4 + j) * TPITCH + 16 * ntA[i] + l15] =
                (short)f2bf(acc[j]);
    }
}

// LDS (shorts): B1t @0 (7040) | Ut @7040 (12160) | Xl aliases Ut head
// (dead after S1, Ut written in S2) | T aliases B1t (dead after S2).
// Total 19200 shorts = 38400 B.
__global__ __launch_bounds__(512, 6) void upfirdn_mfma(
    const float* __restrict__ xin_all,
    const float* __restrict__ bias,
    const short* __restrict__ cws,
    float* __restrict__ out)
{
    __shared__ __align__(16) short SH[19200];
    short* B1t = SH;            // [80][88]
    short* Ut  = SH + 7040;     // [80][152]
    short* Xl  = SH + 7040;     // [80][48], dead after S1
    short* T   = SH;            // [64][88], written in S3

    const int tid  = threadIdx.x;
    const int lane = tid & 63, w = tid >> 6;          // 8 waves
    const int l15  = lane & 15, q4 = lane >> 4;
    const int bx = blockIdx.x, by = blockIdx.y, bc = blockIdx.z;
    const int i0 = by * 64, j0 = bx * 32;

    const short* GtB = cws;
    const short* G2A = cws + 2560;
    const short* DA  = cws + 7168  + (by ? 4096 : 0);
    const short* D2B = cws + 15360 + ((bx == 0) ? 0 : (bx == 3) ? 2 : 1) * 2048;

    // ---- Phase 0: load X tile (crop +1, +bias), pads zero. 80x24 int items. ----
    {
        const float* xp = xin_all + (size_t)bc * (130 * 130);
        const float bv = bias[bc & 63];
        const bool colInt = (bx == 1) | (bx == 2);
        int* Xli = (int*)Xl;
        for (int idx = tid; idx < 1920; idx += 512) {
            int r = idx / 24, cp = idx - r * 24;
            int gr = i0 - 5 + r;
            float f0 = 0.f, f1 = 0.f;
            if (r < 75 && (unsigned)gr < 128u && cp < 22) {
                const float* rowp = xp + (gr + 1) * 130 + 1;
                int gc0 = j0 - 5 + 2 * cp;
                if (colInt) {
                    f0 = rowp[gc0] + bv;
                    if (cp < 21) f1 = rowp[gc0 + 1] + bv;
                } else {
                    if ((unsigned)gc0 < 128u) f0 = rowp[gc0] + bv;
                    if (cp < 21 && (unsigned)(gc0 + 1) < 128u)
                        f1 = rowp[gc0 + 1] + bv;
                }
            }
            Xli[r * 24 + cp] = pack_bf2(f0, f1);
        }
    }
    __syncthreads();

    // ---- S1: 25 tiles. wave 0: t 0..3; wave w>0: t 3w+1 .. 3w+3. ----
    if (w == 0) s1_chunk<4>(0,         GtB, Xl, B1t, lane, l15, q4);
    else        s1_chunk<3>(3 * w + 1, GtB, Xl, B1t, lane, l15, q4);
    __syncthreads();

    // ---- S2: 45 tiles. waves 0..4: 6 tiles @6w; waves 5..7: 5 @5w+5. ----
    if (w < 5) s2_chunk<6>(6 * w,     G2A, B1t, Ut, lane, l15, q4);
    else       s2_chunk<5>(5 * w + 5, G2A, B1t, Ut, lane, l15, q4);
    __syncthreads();

    // ---- S3: 20 tiles. waves 0..3: 3 tiles @3w; waves 4..7: 2 @2w+4. ----
    if (w < 4) s3_chunk<3>(3 * w,     DA, Ut, T, lane, l15, q4);
    else       s3_chunk<2>(2 * w + 4, DA, Ut, T, lane, l15, q4);
    __syncthreads();

    // ---- S4: Out = T * D2t.  8 tiles: wave w -> (mt = w>>1, nt = w&1). ----
    {
        const int mt = w >> 1, nt = w & 1;
        const int k0 = nt ? 16 : 0;
        v8s a0 = *(const v8s*)&T[(16 * mt + l15) * TPITCH + k0 + q4 * 8];
        v8s a1 = *(const v8s*)&T[(16 * mt + l15) * TPITCH + k0 + 32 + q4 * 8];
        v8s b0 = *(const v8s*)&D2B[(nt * 2 + 0) * 512 + lane * 8];
        v8s b1 = *(const v8s*)&D2B[(nt * 2 + 1) * 512 + lane * 8];
        __builtin_amdgcn_sched_barrier(0);
        v4f acc = {0.f, 0.f, 0.f, 0.f};
        acc = __builtin_amdgcn_mfma_f32_16x16x32_bf16(a0, b0, acc, 0, 0, 0);
        acc = __builtin_amdgcn_mfma_f32_16x16x32_bf16(a1, b1, acc, 0, 0, 0);
        float* op = out + (size_t)bc * 16384
                  + (size_t)(i0 + 16 * mt + q4 * 4) * 128 + (j0 + 16 * nt + l15);
#pragma unroll
        for (int i = 0; i < 4; ++i) op[i * 128] = acc[i];
    }
}

extern "C" void kernel_launch(void* const* d_in, const int* in_sizes, int n_in,
                              void* d_out, int out_size, void* d_ws, size_t ws_size,
                              hipStream_t stream) {
    const float* x  = (const float*)d_in[0];
    const float* bs = (const float*)d_in[1];
    const float* fu = (const float*)d_in[2];
    const float* fd = (const float*)d_in[3];
    float* outp = (float*)d_out;
    short* ws = (short*)d_ws;

    build_consts<<<84, 256, 0, stream>>>(fu, fd, ws);    // 21504 elems
    upfirdn_mfma<<<dim3(4, 2, 512), 512, 0, stream>>>(x, bs, ws, outp);
}